// Round 11
// baseline (208.481 us; speedup 1.0000x reference)
//
#include <hip/hip_runtime.h>

typedef _Float16 half8 __attribute__((ext_vector_type(8)));
typedef _Float16 half4 __attribute__((ext_vector_type(4)));
typedef _Float16 half2v __attribute__((ext_vector_type(2)));
typedef float floatx4 __attribute__((ext_vector_type(4)));

// Problem constants: B=2, N=2048, D=1024, H=16, C=3, Dh=64
// q pre-scaled by 0.125*LOG2E; mask & negcp in log2e units -> softmax = exp2(st+m+nc).
#define LOG2E 1.44269504088896f
#define QSCALE 0.18033688011112f   // 0.125 * LOG2E

__device__ __forceinline__ void async16(const void* g, void* l) {
    __builtin_amdgcn_global_load_lds(
        (const __attribute__((address_space(1))) unsigned int*)g,
        (__attribute__((address_space(3))) unsigned int*)l, 16, 0, 0);
}
__device__ __forceinline__ half4 pack4(float a, float b, float c, float d) {
    half2v lo = __builtin_bit_cast(half2v, __builtin_amdgcn_cvt_pkrtz(a, b));
    half2v hi = __builtin_bit_cast(half2v, __builtin_amdgcn_cvt_pkrtz(c, d));
    half4 r; r[0] = lo[0]; r[1] = lo[1]; r[2] = hi[0]; r[3] = hi[1];
    return r;
}

// ---------------- convert x (fp32 -> fp16), 8 elements/thread ----------------
__global__ void k_convert_x(const float* __restrict__ x, _Float16* __restrict__ xh) {
    int i = blockIdx.x * blockDim.x + threadIdx.x;
    const floatx4* xin = (const floatx4*)x;
    floatx4 a = xin[i * 2];
    floatx4 b = xin[i * 2 + 1];
    half8 h;
    h[0] = (_Float16)a[0]; h[1] = (_Float16)a[1]; h[2] = (_Float16)a[2]; h[3] = (_Float16)a[3];
    h[4] = (_Float16)b[0]; h[5] = (_Float16)b[1]; h[6] = (_Float16)b[2]; h[7] = (_Float16)b[3];
    *(half8*)&xh[i * 8] = h;
}

// ---------------- transpose + convert Wqkv [1024,3072] -> Wt fp16 [3072,1024] ----------------
__global__ void k_transpose_w(const float* __restrict__ W, _Float16* __restrict__ Wt) {
    __shared__ float tile[32][33];
    int n0 = blockIdx.x * 32, k0 = blockIdx.y * 32;
    int tx = threadIdx.x, ty = threadIdx.y;  // (32,8)
    #pragma unroll
    for (int r = 0; r < 4; ++r)
        tile[ty + r * 8][tx] = W[(k0 + ty + r * 8) * 3072 + n0 + tx];
    __syncthreads();
    #pragma unroll
    for (int r = 0; r < 4; ++r)
        Wt[(n0 + ty + r * 8) * 1024 + k0 + tx] = (_Float16)tile[tx][ty + r * 8];
}

// ---------------- negcp[b,h,n] = -LOG2E * sum_c coords*rel_weight ----------------
__global__ void k_negcp(const float* __restrict__ coords, const float* __restrict__ rw,
                        float* __restrict__ negcp) {
    int idx = blockIdx.x * 256 + threadIdx.x;       // over B*H*N = 65536
    int bh = idx >> 11, n = idx & 2047;
    int b = bh >> 4, h = bh & 15;
    const float* c = &coords[(b * 2048 + n) * 3];
    const float* w = &rw[h * 3];
    negcp[idx] = -LOG2E * (c[0] * w[0] + c[1] * w[1] + c[2] * w[2]);
}

// ---------------- mask -> fp16*LOG2E, S^T MFMA C-fragment layout (LDS-tiled, coalesced) ----
__global__ void k_prep_mask(const float* __restrict__ mask, _Float16* __restrict__ maskp) {
    __shared__ float tile[64 * 68];
    int tid = threadIdx.x;
    int qt = blockIdx.x >> 5, kt = blockIdx.x & 31;
    int row0 = qt * 64, col0 = kt * 64;
    int lr = tid >> 2, lc = (tid & 3) * 16;
    #pragma unroll
    for (int j = 0; j < 4; ++j)
        *(floatx4*)&tile[lr * 68 + lc + j * 4] =
            *(const floatx4*)&mask[(size_t)(row0 + lr) * 2048 + col0 + lc + j * 4];
    __syncthreads();
    int w = tid >> 6, lane = tid & 63, quad = lane >> 4, l16 = lane & 15;
    half4* outp = (half4*)maskp + (size_t)((qt * 32 + kt) * 4 + w) * 256 + lane;
    #pragma unroll
    for (int t = 0; t < 4; ++t) {
        floatx4 m = *(const floatx4*)&tile[(w * 16 + l16) * 68 + t * 16 + quad * 4];
        outp[t * 64] = pack4(m[0] * LOG2E, m[1] * LOG2E, m[2] * LOG2E, m[3] * LOG2E);
    }
}

// ---------------- fused QKV GEMM: BK=32, double-buffered async staging ----------------
// 768 blocks over all 3072 cols. One barrier/iter; stage(kt+1) drains at next barrier.
// Rows are 32 halves = 4x16B blocks; swizzle quad^(r&3)^((r>>2)&3) -> 2-way (free) b128 reads.
__global__ __launch_bounds__(256) void k_gemm(
    const _Float16* __restrict__ Ah, const _Float16* __restrict__ Bt,
    const float* __restrict__ bias,
    _Float16* __restrict__ qh, _Float16* __restrict__ kh, _Float16* __restrict__ vt) {
    __shared__ _Float16 smem[16384];   // 2 bufs x (As 4096 + Bs 4096) halves = 32 KB
    int tid = threadIdx.x;
    int w = tid >> 6, lane = tid & 63;
    int quad = lane >> 4, l16 = lane & 15;
    int m0 = blockIdx.y * 128;
    int n0 = blockIdx.x * 128;
    bool QK = n0 < 2048;
    int mq = (w >> 1) * 64, nq = (w & 1) * 64;
    int c0 = n0 + nq;

    int rl4 = lane >> 2;            // row within 16-row staging chunk
    int pb4 = lane & 3;             // physical 16B block within 64B row
    floatx4 acc[4][4] = {};

    // staging source pointers (swizzle baked in; bump 32 halves per iter)
    const _Float16* ap[2];
    const _Float16* bp[2];
    #pragma unroll
    for (int j = 0; j < 2; ++j) {
        int row = w * 32 + j * 16 + rl4;
        int lb = pb4 ^ (row & 3) ^ ((row >> 2) & 3);
        ap[j] = Ah + (size_t)(m0 + row) * 1024 + lb * 8;
        bp[j] = Bt + (size_t)(n0 + row) * 1024 + lb * 8;
    }

    #define GSTAGE(buf) {                                      \
        _Float16* As_ = smem + (buf) * 8192;                   \
        _Float16* Bs_ = As_ + 4096;                            \
        async16(ap[0], &As_[(w * 32) * 32]);                   \
        async16(ap[1], &As_[(w * 32 + 16) * 32]);              \
        async16(bp[0], &Bs_[(w * 32) * 32]);                   \
        async16(bp[1], &Bs_[(w * 32 + 16) * 32]);              \
        ap[0] += 32; ap[1] += 32; bp[0] += 32; bp[1] += 32;    \
    }

    #define GBODY(cur, last) {                                                         \
        __syncthreads();                                                               \
        if (!(last)) GSTAGE((cur) ^ 1);                                                \
        const _Float16* As_ = smem + (cur) * 8192;                                     \
        const _Float16* Bs_ = As_ + 4096;                                              \
        half8 af[4], bf[4];                                                            \
        _Pragma("unroll")                                                              \
        for (int s = 0; s < 4; ++s) {                                                  \
            int ra = mq + s * 16 + l16;                                                \
            af[s] = *(const half8*)&As_[ra * 32 +                                      \
                ((quad ^ (ra & 3) ^ ((ra >> 2) & 3)) << 3)];                           \
            int rb = nq + s * 16 + l16;                                                \
            bf[s] = *(const half8*)&Bs_[rb * 32 +                                      \
                ((quad ^ (rb & 3) ^ ((rb >> 2) & 3)) << 3)];                           \
        }                                                                              \
        if (QK) {                                                                      \
            _Pragma("unroll")                                                          \
            for (int ms = 0; ms < 4; ++ms)                                             \
                _Pragma("unroll")                                                      \
                for (int ns = 0; ns < 4; ++ns)                                         \
                    acc[ms][ns] = __builtin_amdgcn_mfma_f32_16x16x32_f16(              \
                        bf[ns], af[ms], acc[ms][ns], 0, 0, 0);                         \
        } else {                                                                       \
            _Pragma("unroll")                                                          \
            for (int ms = 0; ms < 4; ++ms)                                             \
                _Pragma("unroll")                                                      \
                for (int ns = 0; ns < 4; ++ns)                                         \
                    acc[ms][ns] = __builtin_amdgcn_mfma_f32_16x16x32_f16(              \
                        af[ms], bf[ns], acc[ms][ns], 0, 0, 0);                         \
        }                                                                              \
    }

    GSTAGE(0);
    #pragma unroll 1
    for (int kt2 = 0; kt2 < 15; ++kt2) {
        GBODY(0, false);
        GBODY(1, false);
    }
    GBODY(0, false);
    GBODY(1, true);
    #undef GBODY
    #undef GSTAGE

    __syncthreads();   // all waves done reading staging before slab reuse

    // ---- epilogue: wave-private 32x72 slab, 2 passes, coalesced half8 stores ----
    _Float16* Ls = smem + w * 2304;
    int rl = lane >> 3, pb = lane & 7;
    int b = (m0 + mq) >> 11, nbase = (m0 + mq) & 2047;
    if (QK) {
        float qsc = (c0 < 1024) ? QSCALE : 1.0f;    // q heads pre-scaled for softmax
        int h2 = c0 >> 6;                           // 0..31: q heads then k heads
        _Float16* dst = (h2 < 16 ? qh : kh) + (size_t)(((b << 4) + (h2 & 15)) * 2048) * 64;
        int d0 = pb << 3;
        #pragma unroll
        for (int p = 0; p < 2; ++p) {
            #pragma unroll
            for (int ns = 0; ns < 4; ++ns) {
                floatx4 b4 = *(const floatx4*)&bias[c0 + ns * 16 + quad * 4];
                #pragma unroll
                for (int m2 = 0; m2 < 2; ++m2) {
                    int ms = p * 2 + m2;
                    floatx4 v;
                    #pragma unroll
                    for (int i = 0; i < 4; ++i) v[i] = (acc[ms][ns][i] + b4[i]) * qsc;
                    *(half4*)&Ls[(m2 * 16 + l16) * 72 + ns * 16 + quad * 4] =
                        pack4(v[0], v[1], v[2], v[3]);
                }
            }
            #pragma unroll
            for (int rep = 0; rep < 4; ++rep) {
                int nl = rep * 8 + rl;
                half8 v = *(const half8*)&Ls[nl * 72 + d0];
                *(half8*)&dst[(size_t)(nbase + p * 32 + nl) * 64 + d0] = v;
            }
        }
    } else {
        int h = (c0 - 2048) >> 6;
        _Float16* dst = vt + (size_t)(((b << 4) + h) * 64) * 2048;
        int noff = pb << 3;
        #pragma unroll
        for (int p = 0; p < 2; ++p) {
            #pragma unroll
            for (int n2 = 0; n2 < 2; ++n2) {
                int ns = p * 2 + n2;
                float bv = bias[c0 + ns * 16 + l16];
                #pragma unroll
                for (int ms = 0; ms < 4; ++ms) {
                    *(half4*)&Ls[(n2 * 16 + l16) * 72 + ms * 16 + quad * 4] =
                        pack4(acc[ms][ns][0] + bv, acc[ms][ns][1] + bv,
                              acc[ms][ns][2] + bv, acc[ms][ns][3] + bv);
                }
            }
            #pragma unroll
            for (int rep = 0; rep < 4; ++rep) {
                int cl = rep * 8 + rl;
                half8 v = *(const half8*)&Ls[cl * 72 + noff];
                *(half8*)&dst[(size_t)(p * 32 + cl) * 2048 + nbase + noff] = v;
            }
        }
    }
}

// ---------------- flash attention, S^T form, dbuf, unrolled-by-2 (unchanged from R10) ----
__global__ __launch_bounds__(256) void k_attn(
    const _Float16* __restrict__ qh, const _Float16* __restrict__ kh,
    const _Float16* __restrict__ vt, const _Float16* __restrict__ maskp,
    const float* __restrict__ negcp, float* __restrict__ out) {
    __shared__ _Float16 KV[2][8192];   // per buf: K [0,4096), V [4096,8192); 32 KB
    int tid = threadIdx.x;
    int w = tid >> 6, lane = tid & 63;
    int quad = lane >> 4, l16 = lane & 15;
    int rl = lane >> 3, pb = lane & 7;
    int bid = blockIdx.x;
    int qt = bid & 31, bh = bid >> 5;
    int b = bh >> 4, h = bh & 15;
    int qrow = qt * 64 + w * 16;

    half8 qf[2];
    {
        const _Float16* qp = &qh[((size_t)bh * 2048 + qrow + l16) * 64];
        qf[0] = *(const half8*)&qp[quad * 8];
        qf[1] = *(const half8*)&qp[32 + quad * 8];
    }
    floatx4 o[4] = {};
    floatx4 ol = {};                   // ones-MFMA accumulator: every reg = sum_k p
    half4 ones;
    ones[0] = (_Float16)1.f; ones[1] = (_Float16)1.f;
    ones[2] = (_Float16)1.f; ones[3] = (_Float16)1.f;

    int sw = (pb ^ rl) << 3;
    const _Float16* kp0 = kh + (size_t)bh * 131072 + (size_t)(w * 16 + rl) * 64 + sw;
    const _Float16* kp1 = kp0 + 512;                 // +8 rows
    const _Float16* vp0 = vt + (size_t)bh * 131072 + (size_t)(w * 16 + rl) * 2048 + sw;
    const _Float16* vp1 = vp0 + 16384;               // +8 rows
    const half4* mp = (const half4*)maskp + (size_t)(qt * 128 + w) * 256 + lane;
    const float* ncpp = negcp + bh * 2048 + quad * 4;

    #define STAGE(buf) {                                             \
        async16(kp0, &KV[buf][(w * 16) * 64]);                       \
        async16(kp1, &KV[buf][(w * 16 + 8) * 64]);                   \
        async16(vp0, &KV[buf][4096 + (w * 16) * 64]);                \
        async16(vp1, &KV[buf][4096 + (w * 16 + 8) * 64]);            \
        kp0 += 4096; kp1 += 4096; vp0 += 64; vp1 += 64;              \
    }

    #define BODY(cur, last) {                                                          \
        __syncthreads();                                                               \
        if (!(last)) STAGE((cur) ^ 1);                                                 \
        half4 mload[4];                                                                \
        floatx4 ncv[4];                                                                \
        _Pragma("unroll")                                                              \
        for (int t = 0; t < 4; ++t) mload[t] = mp[t * 64];                             \
        _Pragma("unroll")                                                              \
        for (int t = 0; t < 4; ++t) ncv[t] = *(const floatx4*)&ncpp[t * 16];           \
        mp += 1024; ncpp += 64;                                                        \
        floatx4 ci[4];                                                                 \
        _Pragma("unroll")                                                              \
        for (int t = 0; t < 4; ++t)                                                    \
            _Pragma("unroll")                                                          \
            for (int i = 0; i < 4; ++i)                                                \
                ci[t][i] = (float)mload[t][i] + ncv[t][i];                             \
        const _Float16* Ksc = &KV[cur][0];                                             \
        const _Float16* Vsc = &KV[cur][4096];                                          \
        floatx4 st[4];                                                                 \
        _Pragma("unroll")                                                              \
        for (int t = 0; t < 4; ++t) {                                                  \
            int r = t * 16 + l16;                                                      \
            half8 k0 = *(const half8*)&Ksc[r * 64 + ((quad ^ (r & 7)) << 3)];          \
            half8 k1 = *(const half8*)&Ksc[r * 64 + (((quad + 4) ^ (r & 7)) << 3)];    \
            floatx4 z = ci[t];                                                         \
            z = __builtin_amdgcn_mfma_f32_16x16x32_f16(k0, qf[0], z, 0, 0, 0);         \
            z = __builtin_amdgcn_mfma_f32_16x16x32_f16(k1, qf[1], z, 0, 0, 0);         \
            st[t] = z;                                                                 \
        }                                                                              \
        half4 pt[4];                                                                   \
        _Pragma("unroll")                                                              \
        for (int t = 0; t < 4; ++t) {                                                  \
            float p0 = __builtin_amdgcn_exp2f(st[t][0]);                               \
            float p1 = __builtin_amdgcn_exp2f(st[t][1]);                               \
            float p2 = __builtin_amdgcn_exp2f(st[t][2]);                               \
            float p3 = __builtin_amdgcn_exp2f(st[t][3]);                               \
            pt[t] = pack4(p0, p1, p2, p3);                                             \
        }                                                                              \
        _Pragma("unroll")                                                              \
        for (int t = 0; t < 4; ++t)                                                    \
            ol = __builtin_amdgcn_mfma_f32_16x16x16f16(ones, pt[t], ol, 0, 0, 0);      \
        _Pragma("unroll")                                                              \
        for (int dt = 0; dt < 4; ++dt) {                                               \
            int rv = dt * 16 + l16;                                                    \
            _Pragma("unroll")                                                          \
            for (int t = 0; t < 4; ++t) {                                              \
                half4 vf = *(const half4*)&Vsc[rv * 64 +                               \
                    (((t * 2 + (quad >> 1)) ^ (rv & 7)) << 3) + ((quad & 1) << 2)];    \
                o[dt] = __builtin_amdgcn_mfma_f32_16x16x16f16(vf, pt[t], o[dt], 0, 0, 0); \
            }                                                                          \
        }                                                                              \
    }

    STAGE(0);
    #pragma unroll 1
    for (int kt2 = 0; kt2 < 15; ++kt2) {
        BODY(0, false);
        BODY(1, false);
    }
    BODY(0, false);
    BODY(1, true);
    #undef BODY
    #undef STAGE

    float inv = 1.f / ol[0];
    #pragma unroll
    for (int dt = 0; dt < 4; ++dt) {
        floatx4 r;
        #pragma unroll
        for (int i = 0; i < 4; ++i) r[i] = o[dt][i] * inv;
        *(floatx4*)&out[((size_t)(b * 2048 + qrow + l16)) * 1024 + h * 64 + dt * 16 + quad * 4] = r;
    }
}

extern "C" void kernel_launch(void* const* d_in, const int* in_sizes, int n_in,
                              void* d_out, int out_size, void* d_ws, size_t ws_size,
                              hipStream_t stream) {
    const float* x      = (const float*)d_in[0];
    const float* coords = (const float*)d_in[1];
    const float* mask   = (const float*)d_in[2];
    const float* Wqkv   = (const float*)d_in[3];
    const float* bqkv   = (const float*)d_in[4];
    const float* rw     = (const float*)d_in[5];
    float* out = (float*)d_out;

    char* ws = (char*)d_ws;
    _Float16* xh    = (_Float16*)(ws);               // dead after gemm; maskp reuses
    _Float16* maskp = (_Float16*)(ws);
    _Float16* Wt    = (_Float16*)(ws + 8388608);
    _Float16* qh    = (_Float16*)(ws + 14680064);
    _Float16* kh    = (_Float16*)(ws + 23068672);
    _Float16* vt    = (_Float16*)(ws + 31457280);
    float*    ncp   = (float*)(ws + 39845888);

    k_convert_x<<<2048, 256, 0, stream>>>(x, xh);
    k_transpose_w<<<dim3(96, 32), dim3(32, 8), 0, stream>>>(Wqkv, Wt);
    k_negcp<<<256, 256, 0, stream>>>(coords, rw, ncp);
    k_gemm<<<dim3(24, 32), 256, 0, stream>>>(xh, Wt, bqkv, qh, kh, vt);
    k_prep_mask<<<1024, 256, 0, stream>>>(mask, maskp);   // overwrites xh (now dead)
    k_attn<<<1024, 256, 0, stream>>>(qh, kh, vt, maskp, ncp, out);
}

// Round 12
// 197.820 us; speedup vs baseline: 1.0539x; 1.0539x over previous
//
#include <hip/hip_runtime.h>

typedef _Float16 half8 __attribute__((ext_vector_type(8)));
typedef _Float16 half4 __attribute__((ext_vector_type(4)));
typedef _Float16 half2v __attribute__((ext_vector_type(2)));
typedef float floatx4 __attribute__((ext_vector_type(4)));

// Problem constants: B=2, N=2048, D=1024, H=16, C=3, Dh=64
// q pre-scaled by 0.125*LOG2E; mask & negcp in log2e units -> softmax = exp2(st+m+nc).
#define LOG2E 1.44269504088896f
#define QSCALE 0.18033688011112f   // 0.125 * LOG2E

__device__ __forceinline__ void async16(const void* g, void* l) {
    __builtin_amdgcn_global_load_lds(
        (const __attribute__((address_space(1))) unsigned int*)g,
        (__attribute__((address_space(3))) unsigned int*)l, 16, 0, 0);
}
__device__ __forceinline__ half4 pack4(float a, float b, float c, float d) {
    half2v lo = __builtin_bit_cast(half2v, __builtin_amdgcn_cvt_pkrtz(a, b));
    half2v hi = __builtin_bit_cast(half2v, __builtin_amdgcn_cvt_pkrtz(c, d));
    half4 r; r[0] = lo[0]; r[1] = lo[1]; r[2] = hi[0]; r[3] = hi[1];
    return r;
}

// ---------------- fused prep: convert_x | transpose_w | negcp | prep_mask ----------------
// Block ranges: [0,2048) convert_x; [2048,5120) transpose_w; [5120,5376) negcp;
// [5376,6400) prep_mask. All sub-kernels independent; one launch replaces four.
__global__ __launch_bounds__(256) void k_prep(
    const float* __restrict__ x, const float* __restrict__ W,
    const float* __restrict__ coords, const float* __restrict__ rw,
    const float* __restrict__ mask,
    _Float16* __restrict__ xh, _Float16* __restrict__ Wt,
    float* __restrict__ negcp, _Float16* __restrict__ maskp) {
    __shared__ float smem[4352];        // 17.4 KB: prep_mask tile 64x68; transpose 32x33
    int bx = blockIdx.x, tid = threadIdx.x;
    if (bx < 2048) {
        // ---- convert x (fp32 -> fp16), 8 elements/thread ----
        int i = bx * 256 + tid;
        const floatx4* xin = (const floatx4*)x;
        floatx4 a = xin[i * 2];
        floatx4 b = xin[i * 2 + 1];
        half8 h;
        h[0] = (_Float16)a[0]; h[1] = (_Float16)a[1]; h[2] = (_Float16)a[2]; h[3] = (_Float16)a[3];
        h[4] = (_Float16)b[0]; h[5] = (_Float16)b[1]; h[6] = (_Float16)b[2]; h[7] = (_Float16)b[3];
        *(half8*)&xh[i * 8] = h;
    } else if (bx < 5120) {
        // ---- transpose + convert Wqkv [1024,3072] -> Wt fp16 [3072,1024] ----
        int b2 = bx - 2048;
        int n0 = (b2 % 96) * 32, k0 = (b2 / 96) * 32;
        int tx = tid & 31, ty = tid >> 5;   // (32,8)
        float (*tile)[33] = (float(*)[33])smem;
        #pragma unroll
        for (int r = 0; r < 4; ++r)
            tile[ty + r * 8][tx] = W[(size_t)(k0 + ty + r * 8) * 3072 + n0 + tx];
        __syncthreads();
        #pragma unroll
        for (int r = 0; r < 4; ++r)
            Wt[(size_t)(n0 + ty + r * 8) * 1024 + k0 + tx] = (_Float16)tile[tx][ty + r * 8];
    } else if (bx < 5376) {
        // ---- negcp[b,h,n] = -LOG2E * sum_c coords*rel_weight ----
        int idx = (bx - 5120) * 256 + tid;
        int bh = idx >> 11, n = idx & 2047;
        int b = bh >> 4, h = bh & 15;
        const float* c = &coords[(b * 2048 + n) * 3];
        const float* w = &rw[h * 3];
        negcp[idx] = -LOG2E * (c[0] * w[0] + c[1] * w[1] + c[2] * w[2]);
    } else {
        // ---- mask -> fp16*LOG2E, S^T MFMA C-fragment layout ----
        int bid = bx - 5376;
        int qt = bid >> 5, kt = bid & 31;
        int row0 = qt * 64, col0 = kt * 64;
        int lr = tid >> 2, lc = (tid & 3) * 16;
        #pragma unroll
        for (int j = 0; j < 4; ++j)
            *(floatx4*)&smem[lr * 68 + lc + j * 4] =
                *(const floatx4*)&mask[(size_t)(row0 + lr) * 2048 + col0 + lc + j * 4];
        __syncthreads();
        int w = tid >> 6, lane = tid & 63, quad = lane >> 4, l16 = lane & 15;
        half4* outp = (half4*)maskp + (size_t)((qt * 32 + kt) * 4 + w) * 256 + lane;
        #pragma unroll
        for (int t = 0; t < 4; ++t) {
            floatx4 m = *(const floatx4*)&smem[(w * 16 + l16) * 68 + t * 16 + quad * 4];
            outp[t * 64] = pack4(m[0] * LOG2E, m[1] * LOG2E, m[2] * LOG2E, m[3] * LOG2E);
        }
    }
}

// ---------------- fused QKV GEMM: BK=32, double-buffered async staging (R11) ----------------
__global__ __launch_bounds__(256) void k_gemm(
    const _Float16* __restrict__ Ah, const _Float16* __restrict__ Bt,
    const float* __restrict__ bias,
    _Float16* __restrict__ qh, _Float16* __restrict__ kh, _Float16* __restrict__ vt) {
    __shared__ _Float16 smem[16384];   // 2 bufs x (As 4096 + Bs 4096) halves = 32 KB
    int tid = threadIdx.x;
    int w = tid >> 6, lane = tid & 63;
    int quad = lane >> 4, l16 = lane & 15;
    int m0 = blockIdx.y * 128;
    int n0 = blockIdx.x * 128;
    bool QK = n0 < 2048;
    int mq = (w >> 1) * 64, nq = (w & 1) * 64;
    int c0 = n0 + nq;

    int rl4 = lane >> 2;            // row within 16-row staging chunk
    int pb4 = lane & 3;             // physical 16B block within 64B row
    floatx4 acc[4][4] = {};

    const _Float16* ap[2];
    const _Float16* bp[2];
    #pragma unroll
    for (int j = 0; j < 2; ++j) {
        int row = w * 32 + j * 16 + rl4;
        int lb = pb4 ^ (row & 3) ^ ((row >> 2) & 3);
        ap[j] = Ah + (size_t)(m0 + row) * 1024 + lb * 8;
        bp[j] = Bt + (size_t)(n0 + row) * 1024 + lb * 8;
    }

    #define GSTAGE(buf) {                                      \
        _Float16* As_ = smem + (buf) * 8192;                   \
        _Float16* Bs_ = As_ + 4096;                            \
        async16(ap[0], &As_[(w * 32) * 32]);                   \
        async16(ap[1], &As_[(w * 32 + 16) * 32]);              \
        async16(bp[0], &Bs_[(w * 32) * 32]);                   \
        async16(bp[1], &Bs_[(w * 32 + 16) * 32]);              \
        ap[0] += 32; ap[1] += 32; bp[0] += 32; bp[1] += 32;    \
    }

    #define GBODY(cur, last) {                                                         \
        __syncthreads();                                                               \
        if (!(last)) GSTAGE((cur) ^ 1);                                                \
        const _Float16* As_ = smem + (cur) * 8192;                                     \
        const _Float16* Bs_ = As_ + 4096;                                              \
        half8 af[4], bf[4];                                                            \
        _Pragma("unroll")                                                              \
        for (int s = 0; s < 4; ++s) {                                                  \
            int ra = mq + s * 16 + l16;                                                \
            af[s] = *(const half8*)&As_[ra * 32 +                                      \
                ((quad ^ (ra & 3) ^ ((ra >> 2) & 3)) << 3)];                           \
            int rb = nq + s * 16 + l16;                                                \
            bf[s] = *(const half8*)&Bs_[rb * 32 +                                      \
                ((quad ^ (rb & 3) ^ ((rb >> 2) & 3)) << 3)];                           \
        }                                                                              \
        if (QK) {                                                                      \
            _Pragma("unroll")                                                          \
            for (int ms = 0; ms < 4; ++ms)                                             \
                _Pragma("unroll")                                                      \
                for (int ns = 0; ns < 4; ++ns)                                         \
                    acc[ms][ns] = __builtin_amdgcn_mfma_f32_16x16x32_f16(              \
                        bf[ns], af[ms], acc[ms][ns], 0, 0, 0);                         \
        } else {                                                                       \
            _Pragma("unroll")                                                          \
            for (int ms = 0; ms < 4; ++ms)                                             \
                _Pragma("unroll")                                                      \
                for (int ns = 0; ns < 4; ++ns)                                         \
                    acc[ms][ns] = __builtin_amdgcn_mfma_f32_16x16x32_f16(              \
                        af[ms], bf[ns], acc[ms][ns], 0, 0, 0);                         \
        }                                                                              \
    }

    GSTAGE(0);
    #pragma unroll 1
    for (int kt2 = 0; kt2 < 15; ++kt2) {
        GBODY(0, false);
        GBODY(1, false);
    }
    GBODY(0, false);
    GBODY(1, true);
    #undef GBODY
    #undef GSTAGE

    __syncthreads();   // all waves done reading staging before slab reuse

    // ---- epilogue: wave-private 32x72 slab, 2 passes, coalesced half8 stores ----
    _Float16* Ls = smem + w * 2304;
    int rl = lane >> 3, pb = lane & 7;
    int b = (m0 + mq) >> 11, nbase = (m0 + mq) & 2047;
    if (QK) {
        float qsc = (c0 < 1024) ? QSCALE : 1.0f;    // q heads pre-scaled for softmax
        int h2 = c0 >> 6;                           // 0..31: q heads then k heads
        _Float16* dst = (h2 < 16 ? qh : kh) + (size_t)(((b << 4) + (h2 & 15)) * 2048) * 64;
        int d0 = pb << 3;
        #pragma unroll
        for (int p = 0; p < 2; ++p) {
            #pragma unroll
            for (int ns = 0; ns < 4; ++ns) {
                floatx4 b4 = *(const floatx4*)&bias[c0 + ns * 16 + quad * 4];
                #pragma unroll
                for (int m2 = 0; m2 < 2; ++m2) {
                    int ms = p * 2 + m2;
                    floatx4 v;
                    #pragma unroll
                    for (int i = 0; i < 4; ++i) v[i] = (acc[ms][ns][i] + b4[i]) * qsc;
                    *(half4*)&Ls[(m2 * 16 + l16) * 72 + ns * 16 + quad * 4] =
                        pack4(v[0], v[1], v[2], v[3]);
                }
            }
            #pragma unroll
            for (int rep = 0; rep < 4; ++rep) {
                int nl = rep * 8 + rl;
                half8 v = *(const half8*)&Ls[nl * 72 + d0];
                *(half8*)&dst[(size_t)(nbase + p * 32 + nl) * 64 + d0] = v;
            }
        }
    } else {
        int h = (c0 - 2048) >> 6;
        _Float16* dst = vt + (size_t)(((b << 4) + h) * 64) * 2048;
        int noff = pb << 3;
        #pragma unroll
        for (int p = 0; p < 2; ++p) {
            #pragma unroll
            for (int n2 = 0; n2 < 2; ++n2) {
                int ns = p * 2 + n2;
                float bv = bias[c0 + ns * 16 + l16];
                #pragma unroll
                for (int ms = 0; ms < 4; ++ms) {
                    *(half4*)&Ls[(n2 * 16 + l16) * 72 + ms * 16 + quad * 4] =
                        pack4(acc[ms][ns][0] + bv, acc[ms][ns][1] + bv,
                              acc[ms][ns][2] + bv, acc[ms][ns][3] + bv);
                }
            }
            #pragma unroll
            for (int rep = 0; rep < 4; ++rep) {
                int cl = rep * 8 + rl;
                half8 v = *(const half8*)&Ls[cl * 72 + noff];
                *(half8*)&dst[(size_t)(p * 32 + cl) * 2048 + nbase + noff] = v;
            }
        }
    }
}

// ---------------- flash attention, S^T form, dbuf, unrolled-by-2 (unchanged from R10) ----
__global__ __launch_bounds__(256) void k_attn(
    const _Float16* __restrict__ qh, const _Float16* __restrict__ kh,
    const _Float16* __restrict__ vt, const _Float16* __restrict__ maskp,
    const float* __restrict__ negcp, float* __restrict__ out) {
    __shared__ _Float16 KV[2][8192];   // per buf: K [0,4096), V [4096,8192); 32 KB
    int tid = threadIdx.x;
    int w = tid >> 6, lane = tid & 63;
    int quad = lane >> 4, l16 = lane & 15;
    int rl = lane >> 3, pb = lane & 7;
    int bid = blockIdx.x;
    int qt = bid & 31, bh = bid >> 5;
    int b = bh >> 4, h = bh & 15;
    int qrow = qt * 64 + w * 16;

    half8 qf[2];
    {
        const _Float16* qp = &qh[((size_t)bh * 2048 + qrow + l16) * 64];
        qf[0] = *(const half8*)&qp[quad * 8];
        qf[1] = *(const half8*)&qp[32 + quad * 8];
    }
    floatx4 o[4] = {};
    floatx4 ol = {};                   // ones-MFMA accumulator: every reg = sum_k p
    half4 ones;
    ones[0] = (_Float16)1.f; ones[1] = (_Float16)1.f;
    ones[2] = (_Float16)1.f; ones[3] = (_Float16)1.f;

    int sw = (pb ^ rl) << 3;
    const _Float16* kp0 = kh + (size_t)bh * 131072 + (size_t)(w * 16 + rl) * 64 + sw;
    const _Float16* kp1 = kp0 + 512;                 // +8 rows
    const _Float16* vp0 = vt + (size_t)bh * 131072 + (size_t)(w * 16 + rl) * 2048 + sw;
    const _Float16* vp1 = vp0 + 16384;               // +8 rows
    const half4* mp = (const half4*)maskp + (size_t)(qt * 128 + w) * 256 + lane;
    const float* ncpp = negcp + bh * 2048 + quad * 4;

    #define STAGE(buf) {                                             \
        async16(kp0, &KV[buf][(w * 16) * 64]);                       \
        async16(kp1, &KV[buf][(w * 16 + 8) * 64]);                   \
        async16(vp0, &KV[buf][4096 + (w * 16) * 64]);                \
        async16(vp1, &KV[buf][4096 + (w * 16 + 8) * 64]);            \
        kp0 += 4096; kp1 += 4096; vp0 += 64; vp1 += 64;              \
    }

    #define BODY(cur, last) {                                                          \
        __syncthreads();                                                               \
        if (!(last)) STAGE((cur) ^ 1);                                                 \
        half4 mload[4];                                                                \
        floatx4 ncv[4];                                                                \
        _Pragma("unroll")                                                              \
        for (int t = 0; t < 4; ++t) mload[t] = mp[t * 64];                             \
        _Pragma("unroll")                                                              \
        for (int t = 0; t < 4; ++t) ncv[t] = *(const floatx4*)&ncpp[t * 16];           \
        mp += 1024; ncpp += 64;                                                        \
        floatx4 ci[4];                                                                 \
        _Pragma("unroll")                                                              \
        for (int t = 0; t < 4; ++t)                                                    \
            _Pragma("unroll")                                                          \
            for (int i = 0; i < 4; ++i)                                                \
                ci[t][i] = (float)mload[t][i] + ncv[t][i];                             \
        const _Float16* Ksc = &KV[cur][0];                                             \
        const _Float16* Vsc = &KV[cur][4096];                                          \
        floatx4 st[4];                                                                 \
        _Pragma("unroll")                                                              \
        for (int t = 0; t < 4; ++t) {                                                  \
            int r = t * 16 + l16;                                                      \
            half8 k0 = *(const half8*)&Ksc[r * 64 + ((quad ^ (r & 7)) << 3)];          \
            half8 k1 = *(const half8*)&Ksc[r * 64 + (((quad + 4) ^ (r & 7)) << 3)];    \
            floatx4 z = ci[t];                                                         \
            z = __builtin_amdgcn_mfma_f32_16x16x32_f16(k0, qf[0], z, 0, 0, 0);         \
            z = __builtin_amdgcn_mfma_f32_16x16x32_f16(k1, qf[1], z, 0, 0, 0);         \
            st[t] = z;                                                                 \
        }                                                                              \
        half4 pt[4];                                                                   \
        _Pragma("unroll")                                                              \
        for (int t = 0; t < 4; ++t) {                                                  \
            float p0 = __builtin_amdgcn_exp2f(st[t][0]);                               \
            float p1 = __builtin_amdgcn_exp2f(st[t][1]);                               \
            float p2 = __builtin_amdgcn_exp2f(st[t][2]);                               \
            float p3 = __builtin_amdgcn_exp2f(st[t][3]);                               \
            pt[t] = pack4(p0, p1, p2, p3);                                             \
        }                                                                              \
        _Pragma("unroll")                                                              \
        for (int t = 0; t < 4; ++t)                                                    \
            ol = __builtin_amdgcn_mfma_f32_16x16x16f16(ones, pt[t], ol, 0, 0, 0);      \
        _Pragma("unroll")                                                              \
        for (int dt = 0; dt < 4; ++dt) {                                               \
            int rv = dt * 16 + l16;                                                    \
            _Pragma("unroll")                                                          \
            for (int t = 0; t < 4; ++t) {                                              \
                half4 vf = *(const half4*)&Vsc[rv * 64 +                               \
                    (((t * 2 + (quad >> 1)) ^ (rv & 7)) << 3) + ((quad & 1) << 2)];    \
                o[dt] = __builtin_amdgcn_mfma_f32_16x16x16f16(vf, pt[t], o[dt], 0, 0, 0); \
            }                                                                          \
        }                                                                              \
    }

    STAGE(0);
    #pragma unroll 1
    for (int kt2 = 0; kt2 < 15; ++kt2) {
        BODY(0, false);
        BODY(1, false);
    }
    BODY(0, false);
    BODY(1, true);
    #undef BODY
    #undef STAGE

    float inv = 1.f / ol[0];
    #pragma unroll
    for (int dt = 0; dt < 4; ++dt) {
        floatx4 r;
        #pragma unroll
        for (int i = 0; i < 4; ++i) r[i] = o[dt][i] * inv;
        *(floatx4*)&out[((size_t)(b * 2048 + qrow + l16)) * 1024 + h * 64 + dt * 16 + quad * 4] = r;
    }
}

extern "C" void kernel_launch(void* const* d_in, const int* in_sizes, int n_in,
                              void* d_out, int out_size, void* d_ws, size_t ws_size,
                              hipStream_t stream) {
    const float* x      = (const float*)d_in[0];
    const float* coords = (const float*)d_in[1];
    const float* mask   = (const float*)d_in[2];
    const float* Wqkv   = (const float*)d_in[3];
    const float* bqkv   = (const float*)d_in[4];
    const float* rw     = (const float*)d_in[5];
    float* out = (float*)d_out;

    // Workspace layout (maskp no longer aliases xh: both live during the fused prep)
    //   xh   : [0,          8,388,608)
    //   maskp: [8,388,608,  16,777,216)
    //   Wt   : [16,777,216, 23,068,672)
    //   qh   : [23,068,672, 31,457,280)
    //   kh   : [31,457,280, 39,845,888)
    //   vt   : [39,845,888, 48,234,496)
    //   ncp  : [48,234,496, 48,496,640)
    char* ws = (char*)d_ws;
    _Float16* xh    = (_Float16*)(ws);
    _Float16* maskp = (_Float16*)(ws + 8388608);
    _Float16* Wt    = (_Float16*)(ws + 16777216);
    _Float16* qh    = (_Float16*)(ws + 23068672);
    _Float16* kh    = (_Float16*)(ws + 31457280);
    _Float16* vt    = (_Float16*)(ws + 39845888);
    float*    ncp   = (float*)(ws + 48234496);

    k_prep<<<6400, 256, 0, stream>>>(x, Wqkv, coords, rw, mask, xh, Wt, ncp, maskp);
    k_gemm<<<dim3(24, 32), 256, 0, stream>>>(xh, Wt, bqkv, qh, kh, vt);
    k_attn<<<1024, 256, 0, stream>>>(qh, kh, vt, maskp, ncp, out);
}